// Round 2
// baseline (3494.384 us; speedup 1.0000x reference)
//
#include <hip/hip_runtime.h>
#include <hip/hip_bf16.h>

// Problem constants (DeepSeek-V3-style MoE)
#define T 512
#define H 2048
#define E 32
#define KTOP 8
#define I 1408
#define I2 2816          // 2*I
#define NG 8
#define GSZ 4            // E/NG
#define TKG 4
#define CAP 256          // per-expert capacity = 2*T*KTOP/E
#define SI 2816          // I*NS
#define SI2 5632         // 2*I*NS
#define RSF 2.5f

// ---------------------------------------------------------------------------
// Routing: one block (64 threads) per token.
// ---------------------------------------------------------------------------
__global__ __launch_bounds__(64) void route_kernel(
    const float* __restrict__ x, const float* __restrict__ gw,
    const float* __restrict__ bias,
    int* __restrict__ topk_ids, float* __restrict__ topk_w)
{
    const int t = blockIdx.x;
    const int j = threadIdx.x;
    __shared__ float part[64][32];
    __shared__ float sb[32];   // score + bias
    __shared__ float sc[32];   // sigmoid score

    float acc[32];
#pragma unroll
    for (int e = 0; e < 32; ++e) acc[e] = 0.f;

    const float* xr = x + (long)t * H;
    for (int h = j; h < H; h += 64) {
        float xv = xr[h];
        const float* gr = gw + (long)h * E;
#pragma unroll
        for (int e = 0; e < 32; ++e) acc[e] = fmaf(xv, gr[e], acc[e]);
    }
#pragma unroll
    for (int e = 0; e < 32; ++e) part[j][e] = acc[e];
    __syncthreads();

    if (j < 32) {
        float s = 0.f;
        for (int r = 0; r < 64; ++r) s += part[r][j];
        float sig = 1.f / (1.f + expf(-s));
        sc[j] = sig;
        sb[j] = sig + bias[j];
    }
    __syncthreads();

    if (j == 0) {
        // per-group score = sum of top-2 of (score+bias) within group of 4
        float grp[NG];
        for (int g = 0; g < NG; ++g) {
            float m1 = -1e30f, m2 = -1e30f;
            for (int q = 0; q < GSZ; ++q) {
                float v = sb[g * GSZ + q];
                if (v > m1) { m2 = m1; m1 = v; }
                else if (v > m2) { m2 = v; }
            }
            grp[g] = m1 + m2;
        }
        // top-4 groups (stable: strict >)
        bool gsel[NG] = {false, false, false, false, false, false, false, false};
        for (int it = 0; it < TKG; ++it) {
            int best = 0; float bv = -1e30f;
            for (int g = 0; g < NG; ++g)
                if (!gsel[g] && grp[g] > bv) { bv = grp[g]; best = g; }
            gsel[best] = true;
        }
        // top-8 experts among selected groups (stable)
        float masked[E];
        for (int e = 0; e < E; ++e) masked[e] = gsel[e >> 2] ? sb[e] : -1e30f;
        int ids[KTOP]; float ws[KTOP]; float wsum = 0.f;
        for (int k = 0; k < KTOP; ++k) {
            int best = 0; float bv = -1e30f;
            for (int e = 0; e < E; ++e)
                if (masked[e] > bv) { bv = masked[e]; best = e; }
            masked[best] = -1e30f;
            ids[k] = best; ws[k] = sc[best]; wsum += ws[k];
        }
        float inv = RSF / wsum;
        for (int k = 0; k < KTOP; ++k) {
            topk_ids[t * KTOP + k] = ids[k];
            topk_w[t * KTOP + k] = ws[k] * inv;
        }
    }
}

// ---------------------------------------------------------------------------
// Dispatch: replicate cumsum-rank capacity semantics. 1 block, 64 threads.
// ---------------------------------------------------------------------------
__global__ __launch_bounds__(64) void dispatch_kernel(
    const int* __restrict__ topk_ids, const float* __restrict__ topk_w,
    int* __restrict__ slot_tok, float* __restrict__ slot_w)
{
    __shared__ int ids[T * KTOP];
    __shared__ float ws[T * KTOP];
    const int j = threadIdx.x;
    for (int i = j; i < T * KTOP; i += 64) { ids[i] = topk_ids[i]; ws[i] = topk_w[i]; }
    __syncthreads();
    if (j < E) {
        const int e = j;
        for (int c = 0; c < CAP; ++c) { slot_tok[e * CAP + c] = -1; slot_w[e * CAP + c] = 0.f; }
        int cnt = 0;
        for (int i = 0; i < T * KTOP; ++i) {
            if (ids[i] == e) {
                if (cnt < CAP) {
                    slot_tok[e * CAP + cnt] = i >> 3;   // token = i / KTOP
                    slot_w[e * CAP + cnt] = ws[i];
                }
                ++cnt;   // rank counts overflow entries too
            }
        }
    }
}

// ---------------------------------------------------------------------------
// Tiled fp32 GEMM, 128x128 tile, BK=16, 256 threads, 8x8 per thread,
// register prefetch of the next K-slab (global -> reg -> LDS).
// MODE 0: C = A*B (store)           [shared gate_up]
// MODE 1: C += A*B (add)            [shared down -> out]
// MODE 2: gather A rows via slot_tok (expert z), store  [routed w13]
// MODE 3: scatter: out[tok] += w * (A*B)                [routed w2 -> out]
// ---------------------------------------------------------------------------
template <int MODE>
__global__ __launch_bounds__(256) void gemm128(
    const float* __restrict__ Abase, long strideAe, int lda,
    const float* __restrict__ Bbase, long strideBe, int ldb,
    float* __restrict__ Cbase, long strideCe, int ldc,
    int Kdim,
    const int* __restrict__ slot_tok, const float* __restrict__ slot_w)
{
    const int e = blockIdx.z;
    const float* B = Bbase + (long)e * strideBe;
    float* Co = Cbase + (long)e * strideCe;

    __shared__ float As[16][128];   // [k][m]
    __shared__ float Bs[16][128];   // [k][n]

    const int tid = threadIdx.x;
    const int tx = tid & 15, ty = tid >> 4;
    const int m0 = blockIdx.y * 128, n0 = blockIdx.x * 128;

    // A staging: thread -> row (0..127), k-chunk 0 or 8
    const int ar  = tid >> 1;
    const int akc = (tid & 1) * 8;
    // B staging: thread -> k-row (0..15), col-chunk of 8
    const int bkr = tid >> 4;
    const int bc  = (tid & 15) * 8;

    const float* arowp;
    if (MODE == 2) {
        int tok = slot_tok[e * CAP + m0 + ar];
        arowp = (tok >= 0) ? (Abase + (long)tok * lda) : nullptr;
    } else {
        arowp = Abase + (long)e * strideAe + (long)(m0 + ar) * lda;
    }
    const float* brow0 = B + (long)bkr * ldb + n0 + bc;

    float acc[8][8];
#pragma unroll
    for (int i = 0; i < 8; ++i)
#pragma unroll
        for (int j = 0; j < 8; ++j) acc[i][j] = 0.f;

    float4 a0, a1, b0, b1;
    // load first slab
    if (MODE == 2 && arowp == nullptr) {
        a0 = make_float4(0.f, 0.f, 0.f, 0.f); a1 = a0;
    } else {
        a0 = *(const float4*)(arowp + akc);
        a1 = *(const float4*)(arowp + akc + 4);
    }
    b0 = *(const float4*)(brow0);
    b1 = *(const float4*)(brow0 + 4);

    for (int k0 = 0;;) {
        // commit regs -> LDS
        As[akc + 0][ar] = a0.x; As[akc + 1][ar] = a0.y;
        As[akc + 2][ar] = a0.z; As[akc + 3][ar] = a0.w;
        As[akc + 4][ar] = a1.x; As[akc + 5][ar] = a1.y;
        As[akc + 6][ar] = a1.z; As[akc + 7][ar] = a1.w;
        *(float4*)&Bs[bkr][bc]     = b0;
        *(float4*)&Bs[bkr][bc + 4] = b1;
        __syncthreads();

        const int kn = k0 + 16;
        if (kn < Kdim) {   // prefetch next slab into regs while computing
            if (MODE == 2 && arowp == nullptr) {
                a0 = make_float4(0.f, 0.f, 0.f, 0.f); a1 = a0;
            } else {
                a0 = *(const float4*)(arowp + kn + akc);
                a1 = *(const float4*)(arowp + kn + akc + 4);
            }
            b0 = *(const float4*)(brow0 + (long)kn * ldb);
            b1 = *(const float4*)(brow0 + (long)kn * ldb + 4);
        }

#pragma unroll
        for (int k = 0; k < 16; ++k) {
            float4 a0v = *(const float4*)&As[k][ty * 4];
            float4 a1v = *(const float4*)&As[k][64 + ty * 4];
            float4 b0v = *(const float4*)&Bs[k][tx * 4];
            float4 b1v = *(const float4*)&Bs[k][64 + tx * 4];
            float av[8] = {a0v.x, a0v.y, a0v.z, a0v.w, a1v.x, a1v.y, a1v.z, a1v.w};
            float bv[8] = {b0v.x, b0v.y, b0v.z, b0v.w, b1v.x, b1v.y, b1v.z, b1v.w};
#pragma unroll
            for (int i = 0; i < 8; ++i)
#pragma unroll
                for (int j = 0; j < 8; ++j)
                    acc[i][j] = fmaf(av[i], bv[j], acc[i][j]);
        }

        if (kn >= Kdim) break;
        __syncthreads();   // all reads done before overwriting LDS
        k0 = kn;
    }

    // epilogue
#pragma unroll
    for (int i = 0; i < 8; ++i) {
        const int mrow = m0 + ((i < 4) ? (ty * 4 + i) : (64 + ty * 4 + i - 4));
        const int ncol0 = n0 + tx * 4;
        const int ncol1 = n0 + 64 + tx * 4;
        if (MODE == 0 || MODE == 2) {
            *(float4*)&Co[(long)mrow * ldc + ncol0] =
                make_float4(acc[i][0], acc[i][1], acc[i][2], acc[i][3]);
            *(float4*)&Co[(long)mrow * ldc + ncol1] =
                make_float4(acc[i][4], acc[i][5], acc[i][6], acc[i][7]);
        } else if (MODE == 1) {
            float4* p0 = (float4*)&Co[(long)mrow * ldc + ncol0];
            float4* p1 = (float4*)&Co[(long)mrow * ldc + ncol1];
            float4 v0 = *p0, v1 = *p1;
            v0.x += acc[i][0]; v0.y += acc[i][1]; v0.z += acc[i][2]; v0.w += acc[i][3];
            v1.x += acc[i][4]; v1.y += acc[i][5]; v1.z += acc[i][6]; v1.w += acc[i][7];
            *p0 = v0; *p1 = v1;
        } else { // MODE 3: weighted scatter-add to out[tok]
            const int s = e * CAP + mrow;
            const int tok = slot_tok[s];
            if (tok < 0) continue;
            const float w = slot_w[s];
#pragma unroll
            for (int j = 0; j < 4; ++j)
                atomicAdd(&Co[(long)tok * ldc + ncol0 + j], acc[i][j] * w);
#pragma unroll
            for (int j = 0; j < 4; ++j)
                atomicAdd(&Co[(long)tok * ldc + ncol1 + j], acc[i][4 + j] * w);
        }
    }
}

// ---------------------------------------------------------------------------
// In-place SiLU(gate)*up into the gate half of a [rows, ld] gu buffer.
// ---------------------------------------------------------------------------
__global__ __launch_bounds__(256) void act_silu(
    float* __restrict__ gu, int nrows, int half, int ld)
{
    const int per = half >> 2;                 // float4s per row
    const long total = (long)nrows * per;
    long idx = (long)blockIdx.x * blockDim.x + threadIdx.x;
    if (idx >= total) return;
    int r = (int)(idx / per), q = (int)(idx - (long)r * per);
    float* gp = gu + (long)r * ld + q * 4;
    float4 g4 = *(float4*)gp;
    float4 u4 = *(const float4*)(gu + (long)r * ld + half + q * 4);
    g4.x = u4.x * g4.x / (1.f + expf(-g4.x));
    g4.y = u4.y * g4.y / (1.f + expf(-g4.y));
    g4.z = u4.z * g4.z / (1.f + expf(-g4.z));
    g4.w = u4.w * g4.w / (1.f + expf(-g4.w));
    *(float4*)gp = g4;
}

// ---------------------------------------------------------------------------
extern "C" void kernel_launch(void* const* d_in, const int* in_sizes, int n_in,
                              void* d_out, int out_size, void* d_ws, size_t ws_size,
                              hipStream_t stream)
{
    const float* x     = (const float*)d_in[0];
    // d_in[1] residual: unused by reference
    const float* gw    = (const float*)d_in[2];
    const float* bias  = (const float*)d_in[3];
    const float* w13   = (const float*)d_in[4];
    const float* w2    = (const float*)d_in[5];
    const float* sgup  = (const float*)d_in[6];
    const float* sdown = (const float*)d_in[7];
    float* out = (float*)d_out;

    char* p = (char*)d_ws;
    float* topk_w  = (float*)p;  p += (size_t)T * KTOP * 4;
    int*   topk_id = (int*)p;    p += (size_t)T * KTOP * 4;
    int*   slot_tok = (int*)p;   p += (size_t)E * CAP * 4;
    float* slot_w   = (float*)p; p += (size_t)E * CAP * 4;
    float* guA = (float*)p;      p += (size_t)E * CAP * I2 * 4;   // 92.3 MB
    float* sgu = (float*)p;      p += (size_t)T * SI2 * 4;        // 11.5 MB

    hipMemsetAsync(d_out, 0, (size_t)T * H * sizeof(float), stream);

    route_kernel<<<T, 64, 0, stream>>>(x, gw, bias, topk_id, topk_w);
    dispatch_kernel<<<1, 64, 0, stream>>>(topk_id, topk_w, slot_tok, slot_w);

    // routed GEMM1: gu[E*CAP, 2816] = gather(x) @ w13[e]
    gemm128<2><<<dim3(I2 / 128, CAP / 128, E), 256, 0, stream>>>(
        x, 0L, H, w13, (long)H * I2, I2, guA, (long)CAP * I2, I2, H,
        slot_tok, nullptr);

    {   // activation: rows = E*CAP
        long total = (long)E * CAP * (I / 4);
        int blocks = (int)((total + 255) / 256);
        act_silu<<<blocks, 256, 0, stream>>>(guA, E * CAP, I, I2);
    }

    // routed GEMM2 + weighted scatter into out
    gemm128<3><<<dim3(H / 128, CAP / 128, E), 256, 0, stream>>>(
        guA, (long)CAP * I2, I2, w2, (long)I * H, H, out, 0L, H, I,
        slot_tok, slot_w);

    // shared GEMM1: sgu[T, 5632] = x @ shared_gate_up
    gemm128<0><<<dim3(SI2 / 128, T / 128, 1), 256, 0, stream>>>(
        x, 0L, H, sgup, 0L, SI2, sgu, 0L, SI2, H, nullptr, nullptr);

    {   // activation: rows = T
        long total = (long)T * (SI / 4);
        int blocks = (int)((total + 255) / 256);
        act_silu<<<blocks, 256, 0, stream>>>(sgu, T, SI, SI2);
    }

    // shared GEMM2: out += act @ shared_down
    gemm128<1><<<dim3(H / 128, T / 128, 1), 256, 0, stream>>>(
        sgu, 0L, SI2, sdown, 0L, H, out, 0L, H, SI, nullptr, nullptr);
}